// Round 7
// baseline (436.432 us; speedup 1.0000x reference)
//
#include <hip/hip_runtime.h>
#include <hip/hip_bf16.h>
#include <hip/hip_fp16.h>

// GCNDecoder: 2-layer GCN, N=100000, E=1600000, 64 -> 128 -> 64, fp32.
//
// R1: agg-before-GEMM (linearity), dst-CSR + gather agg (no fp32 atomics).
// R2/R4: XCD-partitioned fill + nt loads -- WRITE only 105->72->64 MB.
// R3: f16 gather features (agg FETCH at the 8-L2 floor ~96 MB).
// R5: agg 8-edge MLP unroll (agg 81 -> <79 us); nt-on-reused-lines lesson.
// R6: fill restructured two-phase. Root cause of fill's 64 MB WRITE: each
//     partition streamed the WHOLE 12.8 MB edge list through its 4 MB L2,
//     continuously evicting dirty sorted_src lines (~10x write amp). Now:
//     bin_kernel does ONE pass binning (src,dst) into 8 contiguous per-
//     partition buckets (LDS counting-sort, coalesced flush; bucket bases
//     are exact = row_start[p*psz]); fill2 has partition p stream only its
//     own ~1.6 MB bucket -> working set ~2.5 MB < 4 MB L2, ~1x write amp.
//
// Pipeline:
//   cvt(x->xh f16) -> zero_cnt -> hist(dst,nt) -> scan1/2/3 (+bcur init)
//   -> bin(ebuf) -> fill2(sorted_src) -> agg(xh -> agg_x f16)
//   -> gemm1 (r = relu(agg_x W3 + b3), f16) -> gemm2 (t = r W4, f16)
//   -> agg(t -> out f32, +b4)

constexpr int IN_C  = 64;
constexpr int HID_C = 128;
constexpr int OUT_C = 64;
constexpr int NPART = 8;            // XCD count
constexpr int TILE  = 2048;         // bin tile = 8 edges/thread * 256

typedef int v4i __attribute__((ext_vector_type(4)));

__device__ __forceinline__ float2 up2(unsigned u) {      // unpack f16x2
    __half2 h = *reinterpret_cast<__half2*>(&u);
    return __half22float2(h);
}
__device__ __forceinline__ unsigned pk2(float a, float b) {  // pack f16x2
    __half2 h = __float22half2_rn(make_float2(a, b));
    return *reinterpret_cast<unsigned*>(&h);
}

// Pack 2 consecutive fp32 channels into one u32 of f16 pairs.
__global__ __launch_bounds__(256) void cvt_kernel(
    const float2* __restrict__ in, unsigned* __restrict__ outw, int nw)
{
    int i = blockIdx.x * 256 + threadIdx.x;
    if (i < nw) {
        float2 v = in[i];
        outw[i] = pk2(v.x, v.y);
    }
}

__global__ __launch_bounds__(256) void zero_cnt_kernel(int* __restrict__ cnt, int n)
{
    int i = blockIdx.x * 256 + threadIdx.x;
    if (i < n) cnt[i] = 0;
}

__global__ __launch_bounds__(256) void hist_kernel(
    const int* __restrict__ dst, int* __restrict__ cnt, int E)
{
    int e = blockIdx.x * 256 + threadIdx.x;
    if (e < E) {
        int d = __builtin_nontemporal_load(&dst[e]);
        atomicAdd(&cnt[d], 1);
    }
}

__global__ __launch_bounds__(256) void scan1_kernel(
    const int* __restrict__ cnt, int* __restrict__ row_start,
    int* __restrict__ partials, int n)
{
    __shared__ int s[256];
    int i = blockIdx.x * 256 + threadIdx.x;
    int v = (i < n) ? cnt[i] : 0;
    s[threadIdx.x] = v;
    __syncthreads();
    for (int off = 1; off < 256; off <<= 1) {
        int t = (threadIdx.x >= off) ? s[threadIdx.x - off] : 0;
        __syncthreads();
        s[threadIdx.x] += t;
        __syncthreads();
    }
    if (i < n) row_start[i] = s[threadIdx.x] - v;
    if (threadIdx.x == 255) partials[blockIdx.x] = s[255];
}

__global__ __launch_bounds__(512) void scan2_kernel(int* __restrict__ partials, int nb)
{
    __shared__ int s[512];
    int v = (threadIdx.x < nb) ? partials[threadIdx.x] : 0;
    s[threadIdx.x] = v;
    __syncthreads();
    for (int off = 1; off < 512; off <<= 1) {
        int t = (threadIdx.x >= off) ? s[threadIdx.x - off] : 0;
        __syncthreads();
        s[threadIdx.x] += t;
        __syncthreads();
    }
    if (threadIdx.x < nb) partials[threadIdx.x] = s[threadIdx.x] - v;
}

// Finalize row_start/cursor/dinv; also init per-partition bucket cursors
// bcur[p] = row_start[p*psz] (exact bucket bases for bin_kernel).
__global__ __launch_bounds__(256) void scan3_kernel(
    const int* __restrict__ cnt, int* __restrict__ row_start,
    const int* __restrict__ partials, int* __restrict__ cursor,
    float* __restrict__ dinv, int* __restrict__ bcur, int n, int E, int psz)
{
    int i = blockIdx.x * 256 + threadIdx.x;
    if (i < n) {
        int rs = row_start[i] + partials[i >> 8];
        row_start[i] = rs;
        cursor[i] = rs;
        dinv[i] = rsqrtf((float)cnt[i] + 1.0f);   // +1: self-loop
        if (i % psz == 0) bcur[i / psz] = rs;
    }
    if (i == 0) row_start[n] = E;
}

// Phase A: bin (src,dst) pairs into 8 contiguous per-partition buckets of
// ebuf. LDS counting-sort per 2048-edge tile; flush coalesced. Bucket sizes
// are exact by construction (same d/psz as region sizing), no overflow.
__global__ __launch_bounds__(256) void bin_kernel(
    const int* __restrict__ src, const int* __restrict__ dst,
    int* __restrict__ bcur, int2* __restrict__ ebuf, int E, int psz)
{
    __shared__ int2 stage[TILE];                 // 16 KB
    __shared__ int lcnt[NPART], lofs[NPART], lpos[NPART], gbase[NPART];
    const int base = blockIdx.x * TILE;
    const int cnt_mine = min(TILE, E - base);
    if (threadIdx.x < NPART) lcnt[threadIdx.x] = 0;
    __syncthreads();
    int s[8], d[8], p[8];
    #pragma unroll
    for (int k = 0; k < 8; ++k) {
        int jo = threadIdx.x + k * 256;
        if (jo < cnt_mine) {
            s[k] = __builtin_nontemporal_load(&src[base + jo]);
            d[k] = __builtin_nontemporal_load(&dst[base + jo]);
            p[k] = d[k] / psz;
            atomicAdd(&lcnt[p[k]], 1);
        } else p[k] = -1;
    }
    __syncthreads();
    if (threadIdx.x == 0) {
        int acc = 0;
        #pragma unroll
        for (int b = 0; b < NPART; ++b) {
            lofs[b] = acc; lpos[b] = acc; acc += lcnt[b];
        }
    }
    __syncthreads();
    // reserve global chunks (stable lcnt) + place into LDS, concurrently
    if (threadIdx.x < NPART)
        gbase[threadIdx.x] = atomicAdd(&bcur[threadIdx.x], lcnt[threadIdx.x]);
    #pragma unroll
    for (int k = 0; k < 8; ++k) {
        if (p[k] >= 0) {
            int pos = atomicAdd(&lpos[p[k]], 1);
            stage[pos] = make_int2(s[k], d[k]);
        }
    }
    __syncthreads();
    // flush: LDS is bucket-sorted -> consecutive j map to consecutive global
    for (int j = threadIdx.x; j < cnt_mine; j += 256) {
        int b = 0;
        #pragma unroll
        for (int q = 1; q < NPART; ++q) if (j >= lofs[q]) b = q;
        ebuf[gbase[b] + (j - lofs[b])] = stage[j];
    }
}

// Phase B: partition p (blockIdx%8 -> XCD heuristic) streams ONLY its own
// bucket (~1.6 MB) and scatters into its sorted_src slice (~800 KB) +
// cursor slice (~50 KB): whole working set fits one XCD's 4 MB L2.
__global__ __launch_bounds__(256) void fill2_kernel(
    const int2* __restrict__ ebuf, const int* __restrict__ row_start,
    int* __restrict__ cursor, int* __restrict__ sorted_src, int n, int psz)
{
    const int p  = blockIdx.x & (NPART - 1);
    const int q  = blockIdx.x / NPART;
    const int QB = gridDim.x / NPART;
    const int lo = p * psz;
    const int hi = min(lo + psz, n);
    const int beg = row_start[lo], end = row_start[hi];
    for (int j = beg + q * 256 + threadIdx.x; j < end; j += QB * 256) {
        int2 e = ebuf[j];
        int pos = atomicAdd(&cursor[e.y], 1);
        sorted_src[pos] = e.x;
    }
}

// One wave per dst node. feat is packed f16 (32 u32 words / row = 64 ch).
// Half-wave-per-edge; 4x unroll per half = 8 edges in flight (MLP).
// out[d] = dinv_d*(feat[d]*dinv_d + sum_s feat[s]*dinv_s) [+ bias].
template <bool OUT_F16, bool ADD_BIAS>
__global__ __launch_bounds__(256) void agg_f16_kernel(
    const unsigned* __restrict__ feat, const int* __restrict__ row_start,
    const int* __restrict__ sorted_src, const float* __restrict__ dinv,
    const float* __restrict__ bias, void* __restrict__ outp, int n)
{
    const int wv   = threadIdx.x >> 6;
    const int lane = threadIdx.x & 63;
    const int half = lane >> 5;
    const int lc   = lane & 31;
    const int d    = blockIdx.x * 4 + wv;
    if (d >= n) return;                 // wave-uniform exit
    const float di = dinv[d];
    float ax = 0.0f, ay = 0.0f;
    if (half == 0) {                    // self-loop term (once)
        float2 f = up2(feat[(size_t)d * 32 + lc]);
        ax = f.x * di;
        ay = f.y * di;
    }
    const int beg = row_start[d], end = row_start[d + 1];
    int i = beg + half;
    for (; i + 6 < end; i += 8) {       // 4 edges per half, batch-issued
        int s0 = sorted_src[i];
        int s1 = sorted_src[i + 2];
        int s2 = sorted_src[i + 4];
        int s3 = sorted_src[i + 6];
        float w0 = dinv[s0], w1 = dinv[s1], w2 = dinv[s2], w3 = dinv[s3];
        unsigned u0 = feat[(size_t)s0 * 32 + lc];
        unsigned u1 = feat[(size_t)s1 * 32 + lc];
        unsigned u2 = feat[(size_t)s2 * 32 + lc];
        unsigned u3 = feat[(size_t)s3 * 32 + lc];
        float2 f0 = up2(u0), f1 = up2(u1), f2 = up2(u2), f3 = up2(u3);
        ax += f0.x * w0; ay += f0.y * w0;
        ax += f1.x * w1; ay += f1.y * w1;
        ax += f2.x * w2; ay += f2.y * w2;
        ax += f3.x * w3; ay += f3.y * w3;
    }
    for (; i < end; i += 2) {           // remainder (each half strides 2)
        int s0 = sorted_src[i];
        float w0 = dinv[s0];
        float2 f0 = up2(feat[(size_t)s0 * 32 + lc]);
        ax += f0.x * w0; ay += f0.y * w0;
    }
    float ox = ax + __shfl(ax, lane + 32);
    float oy = ay + __shfl(ay, lane + 32);
    if (half == 0) {
        ox *= di; oy *= di;
        if (ADD_BIAS) {
            const float2 bv = ((const float2*)bias)[lc];
            ox += bv.x; oy += bv.y;
        }
        if (OUT_F16) ((unsigned*)outp)[(size_t)d * 32 + lc] = pk2(ox, oy);
        else         ((float2*)outp)[(size_t)d * 32 + lc] = make_float2(ox, oy);
    }
}

// r[row][c] = relu(sum_k agg_x[row][k] * W3[k][c] + b3[c]), r stored f16x2.
// 64 rows x 128 cols / block; per thread 8 cols x 4 rows (FMA-bound).
__global__ __launch_bounds__(256) void gemm1_kernel(
    const unsigned* __restrict__ xh, const float* __restrict__ W,
    const float* __restrict__ b, unsigned* __restrict__ rout, int n)
{
    __shared__ float Ws[IN_C * HID_C];   // [k][c] f32, 32 KB
    __shared__ float xs[64][IN_C + 1];   // 16.6 KB
    for (int i = threadIdx.x; i < IN_C * HID_C; i += 256) Ws[i] = W[i];
    const int r0 = blockIdx.x * 64;
    for (int i = threadIdx.x; i < 64 * 32; i += 256) {
        int row = i >> 5, c = i & 31;
        int r = r0 + row;
        float2 f = up2((r < n) ? xh[(size_t)r * 32 + c] : 0u);
        xs[row][c * 2]     = f.x;
        xs[row][c * 2 + 1] = f.y;
    }
    __syncthreads();
    const int ct = threadIdx.x & 15;   // 16 x 8 = 128 cols
    const int rt = threadIdx.x >> 4;   // 16 x 4 = 64 rows
    float acc[4][8] = {};
    const float4* Ws4 = (const float4*)Ws;
    for (int k = 0; k < IN_C; ++k) {
        float4 w0 = Ws4[k * 32 + ct * 2];
        float4 w1 = Ws4[k * 32 + ct * 2 + 1];
        #pragma unroll
        for (int ry = 0; ry < 4; ++ry) {
            float xv = xs[rt * 4 + ry][k];
            acc[ry][0] += xv * w0.x; acc[ry][1] += xv * w0.y;
            acc[ry][2] += xv * w0.z; acc[ry][3] += xv * w0.w;
            acc[ry][4] += xv * w1.x; acc[ry][5] += xv * w1.y;
            acc[ry][6] += xv * w1.z; acc[ry][7] += xv * w1.w;
        }
    }
    float4 b0 = ((const float4*)b)[ct * 2];
    float4 b1 = ((const float4*)b)[ct * 2 + 1];
    #pragma unroll
    for (int ry = 0; ry < 4; ++ry) {
        int r = r0 + rt * 4 + ry;
        if (r < n) {
            uint4 o;
            o.x = pk2(fmaxf(acc[ry][0] + b0.x, 0.0f), fmaxf(acc[ry][1] + b0.y, 0.0f));
            o.y = pk2(fmaxf(acc[ry][2] + b0.z, 0.0f), fmaxf(acc[ry][3] + b0.w, 0.0f));
            o.z = pk2(fmaxf(acc[ry][4] + b1.x, 0.0f), fmaxf(acc[ry][5] + b1.y, 0.0f));
            o.w = pk2(fmaxf(acc[ry][6] + b1.z, 0.0f), fmaxf(acc[ry][7] + b1.w, 0.0f));
            *(uint4*)&rout[(size_t)r * 64 + ct * 4] = o;
        }
    }
}

// t[row][c] = sum_k r[row][k] * W4[k][c], t stored f16x2 (into xh buffer).
// 64 rows x 64 cols / block; per thread 8 cols x 2 rows; W4 staged f16 in LDS.
__global__ __launch_bounds__(256) void gemm2_kernel(
    const unsigned* __restrict__ rin, const float* __restrict__ W,
    unsigned* __restrict__ tout, int n)
{
    __shared__ unsigned Wh[HID_C * 32];  // f16x2 [k][c/2], 16 KB
    __shared__ float xs[64][HID_C + 1];  // 33 KB
    for (int i = threadIdx.x; i < HID_C * 32; i += 256) {
        int k = i >> 5, cp = i & 31;
        Wh[i] = pk2(W[k * OUT_C + cp * 2], W[k * OUT_C + cp * 2 + 1]);
    }
    const int r0 = blockIdx.x * 64;
    for (int i = threadIdx.x; i < 64 * 64; i += 256) {
        int row = i >> 6, c = i & 63;
        int r = r0 + row;
        float2 f = up2((r < n) ? rin[(size_t)r * 64 + c] : 0u);
        xs[row][c * 2]     = f.x;
        xs[row][c * 2 + 1] = f.y;
    }
    __syncthreads();
    const int ct = threadIdx.x & 7;    // 8 x 8 = 64 cols
    const int rt = threadIdx.x >> 3;   // 32 x 2 = 64 rows
    float acc[2][8] = {};
    for (int k = 0; k < HID_C; ++k) {
        uint4 wq = *(const uint4*)&Wh[k * 32 + ct * 4];
        float2 wa = up2(wq.x), wb = up2(wq.y), wc = up2(wq.z), wd = up2(wq.w);
        #pragma unroll
        for (int ry = 0; ry < 2; ++ry) {
            float xv = xs[rt * 2 + ry][k];
            acc[ry][0] += xv * wa.x; acc[ry][1] += xv * wa.y;
            acc[ry][2] += xv * wb.x; acc[ry][3] += xv * wb.y;
            acc[ry][4] += xv * wc.x; acc[ry][5] += xv * wc.y;
            acc[ry][6] += xv * wd.x; acc[ry][7] += xv * wd.y;
        }
    }
    #pragma unroll
    for (int ry = 0; ry < 2; ++ry) {
        int r = r0 + rt * 2 + ry;
        if (r < n) {
            uint4 o;
            o.x = pk2(acc[ry][0], acc[ry][1]);
            o.y = pk2(acc[ry][2], acc[ry][3]);
            o.z = pk2(acc[ry][4], acc[ry][5]);
            o.w = pk2(acc[ry][6], acc[ry][7]);
            *(uint4*)&tout[(size_t)r * 32 + ct * 4] = o;
        }
    }
}

extern "C" void kernel_launch(void* const* d_in, const int* in_sizes, int n_in,
                              void* d_out, int out_size, void* d_ws, size_t ws_size,
                              hipStream_t stream)
{
    const float* x  = (const float*)d_in[0];
    const int*   ei = (const int*)d_in[1];
    const float* W3 = (const float*)d_in[2];
    const float* b3 = (const float*)d_in[3];
    const float* W4 = (const float*)d_in[4];
    const float* b4 = (const float*)d_in[5];
    float* out = (float*)d_out;

    const int n = in_sizes[0] / IN_C;   // 100000
    const int E = in_sizes[1] / 2;      // 1600000
    const int* src = ei;
    const int* dst = ei + E;
    const int psz = (n + NPART - 1) / NPART;   // 12500

    const size_t n_pad = ((size_t)n + 256) & ~(size_t)255;  // room for row_start[n]

    // Workspace: cnt | row_start | cursor | partials(512) | bcur(256) | dinv |
    //            ssrc | ebuf (E int2) | xh (n*32 u32, reused as t) |
    //            agg_x (n*32 u32) | r (n*64 u32)
    int*      cnt       = (int*)d_ws;
    int*      row_start = cnt + n_pad;
    int*      cursor    = row_start + n_pad;
    int*      partials  = cursor + n_pad;
    int*      bcur      = partials + 512;
    float*    dinv      = (float*)(bcur + 256);
    int*      ssrc      = (int*)(dinv + n_pad);
    int2*     ebuf      = (int2*)(ssrc + (((size_t)E + 255) & ~(size_t)255));
    unsigned* xh        = (unsigned*)(ebuf + (size_t)E);
    unsigned* agg_x     = xh + n_pad * 32;
    unsigned* r         = agg_x + n_pad * 32;
    unsigned* t         = xh;                      // xh dead after agg1

    const int nb  = (n + 255) / 256;   // 391
    const int neb = (E + 255) / 256;

    cvt_kernel<<<(n * 32 + 255) / 256, 256, 0, stream>>>(
        (const float2*)x, xh, n * 32);

    zero_cnt_kernel<<<nb, 256, 0, stream>>>(cnt, n);
    hist_kernel<<<neb, 256, 0, stream>>>(dst, cnt, E);
    scan1_kernel<<<nb, 256, 0, stream>>>(cnt, row_start, partials, n);
    scan2_kernel<<<1, 512, 0, stream>>>(partials, nb);
    scan3_kernel<<<nb, 256, 0, stream>>>(cnt, row_start, partials, cursor,
                                         dinv, bcur, n, E, psz);

    bin_kernel<<<(E + TILE - 1) / TILE, 256, 0, stream>>>(src, dst, bcur, ebuf, E, psz);
    fill2_kernel<<<NPART * 64, 256, 0, stream>>>(ebuf, row_start, cursor, ssrc, n, psz);

    agg_f16_kernel<true, false><<<(n + 3) / 4, 256, 0, stream>>>(
        xh, row_start, ssrc, dinv, nullptr, agg_x, n);

    gemm1_kernel<<<(n + 63) / 64, 256, 0, stream>>>(agg_x, W3, b3, r, n);
    gemm2_kernel<<<(n + 63) / 64, 256, 0, stream>>>(r, W4, t, n);

    agg_f16_kernel<false, true><<<(n + 3) / 4, 256, 0, stream>>>(
        t, row_start, ssrc, dinv, b4, out, n);
}

// Round 8
// 388.118 us; speedup vs baseline: 1.1245x; 1.1245x over previous
//
#include <hip/hip_runtime.h>
#include <hip/hip_bf16.h>
#include <hip/hip_fp16.h>

// GCNDecoder: 2-layer GCN, N=100000, E=1600000, 64 -> 128 -> 64, fp32.
//
// R1: agg-before-GEMM (linearity), dst-CSR + gather agg (no fp32 atomics).
// R2/R4/R6: tried XCD-affinity scatter (blockIdx%8): WRITE stuck at 65-72 MB.
//   R7 POST-MORTEM: fill2 FETCH dropped to 6.9 MB (binning works) but WRITE
//   stayed 65 MB -> the blockIdx%8->XCD mapping assumption is FALSE; random
//   4B stores keep coming from all 8 non-coherent L2s (~10x line-level write
//   amplification). Lesson: never rely on workgroup->XCD placement; make
//   scatter writes structurally coalesced.
// R3: f16 gather features (agg FETCH at the 8-L2 floor ~96 MB).
// R5: agg 8-edge MLP unroll; nt-on-reused-lines regression lesson.
// R7: counting sort with LDS-staged final scatter. bin: 196 buckets of 512
//   dst nodes (d>>9), 4096-edge tiles, bucket-grouped LDS flush (~168 B per
//   bucket per tile). fill3: one block per bucket; local cursors + whole
//   output region (avg 8.2K edges, cap 16K) in LDS; random placement done
//   with LDS atomics; single coalesced HBM write of the region. No random
//   HBM writes anywhere -> write amp ~1x by construction.
//
// Pipeline:
//   cvt(x->xh f16) -> zero_cnt -> hist(dst,nt) -> scan1/2/3 (+bcur init)
//   -> bin(ebuf, 196 buckets) -> fill3(sorted_src, LDS-staged)
//   -> agg(xh -> agg_x f16) -> gemm1 (r = relu(agg_x W3 + b3), f16)
//   -> gemm2 (t = r W4, f16) -> agg(t -> out f32, +b4)

constexpr int IN_C  = 64;
constexpr int HID_C = 128;
constexpr int OUT_C = 64;
constexpr int BSHIFT = 9;                 // bucket width = 512 dst nodes
constexpr int BW     = 1 << BSHIFT;
constexpr int TILE   = 4096;              // bin tile (edges)
constexpr int FCAP   = 16384;             // fill3 LDS region cap (64 KB)

typedef int v4i __attribute__((ext_vector_type(4)));

__device__ __forceinline__ float2 up2(unsigned u) {      // unpack f16x2
    __half2 h = *reinterpret_cast<__half2*>(&u);
    return __half22float2(h);
}
__device__ __forceinline__ unsigned pk2(float a, float b) {  // pack f16x2
    __half2 h = __float22half2_rn(make_float2(a, b));
    return *reinterpret_cast<unsigned*>(&h);
}

// Pack 2 consecutive fp32 channels into one u32 of f16 pairs.
__global__ __launch_bounds__(256) void cvt_kernel(
    const float2* __restrict__ in, unsigned* __restrict__ outw, int nw)
{
    int i = blockIdx.x * 256 + threadIdx.x;
    if (i < nw) {
        float2 v = in[i];
        outw[i] = pk2(v.x, v.y);
    }
}

__global__ __launch_bounds__(256) void zero_cnt_kernel(int* __restrict__ cnt, int n)
{
    int i = blockIdx.x * 256 + threadIdx.x;
    if (i < n) cnt[i] = 0;
}

__global__ __launch_bounds__(256) void hist_kernel(
    const int* __restrict__ dst, int* __restrict__ cnt, int E)
{
    int e = blockIdx.x * 256 + threadIdx.x;
    if (e < E) {
        int d = __builtin_nontemporal_load(&dst[e]);
        atomicAdd(&cnt[d], 1);
    }
}

__global__ __launch_bounds__(256) void scan1_kernel(
    const int* __restrict__ cnt, int* __restrict__ row_start,
    int* __restrict__ partials, int n)
{
    __shared__ int s[256];
    int i = blockIdx.x * 256 + threadIdx.x;
    int v = (i < n) ? cnt[i] : 0;
    s[threadIdx.x] = v;
    __syncthreads();
    for (int off = 1; off < 256; off <<= 1) {
        int t = (threadIdx.x >= off) ? s[threadIdx.x - off] : 0;
        __syncthreads();
        s[threadIdx.x] += t;
        __syncthreads();
    }
    if (i < n) row_start[i] = s[threadIdx.x] - v;
    if (threadIdx.x == 255) partials[blockIdx.x] = s[255];
}

__global__ __launch_bounds__(512) void scan2_kernel(int* __restrict__ partials, int nb)
{
    __shared__ int s[512];
    int v = (threadIdx.x < nb) ? partials[threadIdx.x] : 0;
    s[threadIdx.x] = v;
    __syncthreads();
    for (int off = 1; off < 512; off <<= 1) {
        int t = (threadIdx.x >= off) ? s[threadIdx.x - off] : 0;
        __syncthreads();
        s[threadIdx.x] += t;
        __syncthreads();
    }
    if (threadIdx.x < nb) partials[threadIdx.x] = s[threadIdx.x] - v;
}

// Finalize row_start/cursor/dinv; init per-bucket cursors
// bcur[b] = row_start[b*BW] (exact bucket bases for bin_kernel).
__global__ __launch_bounds__(256) void scan3_kernel(
    const int* __restrict__ cnt, int* __restrict__ row_start,
    const int* __restrict__ partials, int* __restrict__ cursor,
    float* __restrict__ dinv, int* __restrict__ bcur, int n, int E)
{
    int i = blockIdx.x * 256 + threadIdx.x;
    if (i < n) {
        int rs = row_start[i] + partials[i >> 8];
        row_start[i] = rs;
        cursor[i] = rs;
        dinv[i] = rsqrtf((float)cnt[i] + 1.0f);   // +1: self-loop
        if ((i & (BW - 1)) == 0) bcur[i >> BSHIFT] = rs;
    }
    if (i == 0) row_start[n] = E;
}

// Bin (src,dst) into 196 contiguous per-bucket regions of ebuf (bucket =
// dst>>9; region base/size exact via row_start). Two LDS stages: raw, then
// bucket-grouped; flush is coalesced (~21 edges/bucket/tile).
__global__ __launch_bounds__(256) void bin_kernel(
    const int* __restrict__ src, const int* __restrict__ dst,
    int* __restrict__ bcur, int2* __restrict__ ebuf, int E, int nbkt)
{
    __shared__ int2 stageR[TILE];             // 32 KB raw
    __shared__ int2 stageS[TILE];             // 32 KB bucket-grouped
    __shared__ int lcnt[256], lofs[256], lpos[256], gbase[256];
    const int base = blockIdx.x * TILE;
    const int cnt_mine = min(TILE, E - base);
    for (int b = threadIdx.x; b < nbkt; b += 256) lcnt[b] = 0;
    __syncthreads();
    for (int jo = threadIdx.x; jo < cnt_mine; jo += 256) {
        int s = __builtin_nontemporal_load(&src[base + jo]);
        int d = __builtin_nontemporal_load(&dst[base + jo]);
        stageR[jo] = make_int2(s, d);
        atomicAdd(&lcnt[d >> BSHIFT], 1);
    }
    __syncthreads();
    if (threadIdx.x == 0) {                   // serial prefix over 196 buckets
        int acc = 0;
        for (int b = 0; b < nbkt; ++b) { lofs[b] = acc; lpos[b] = acc; acc += lcnt[b]; }
    }
    __syncthreads();
    if (threadIdx.x < nbkt)
        gbase[threadIdx.x] = atomicAdd(&bcur[threadIdx.x], lcnt[threadIdx.x]);
    for (int jo = threadIdx.x; jo < cnt_mine; jo += 256) {
        int2 e = stageR[jo];
        int pos = atomicAdd(&lpos[e.y >> BSHIFT], 1);
        stageS[pos] = e;
    }
    __syncthreads();
    for (int j = threadIdx.x; j < cnt_mine; j += 256) {
        int2 e = stageS[j];
        int b = e.y >> BSHIFT;
        ebuf[gbase[b] + (j - lofs[b])] = e;
    }
}

// One block per bucket. Output region [row_start[lo], row_start[hi]) is
// contiguous (avg 8.2K edges); random placement happens in LDS (local
// cursor atomics), then ONE coalesced stream write. Fallback to global
// cursor atomics only if region exceeds FCAP (never on this graph).
__global__ __launch_bounds__(256) void fill3_kernel(
    const int2* __restrict__ ebuf, const int* __restrict__ row_start,
    int* __restrict__ cursor, int* __restrict__ sorted_src, int n)
{
    __shared__ int lcur[BW];
    __shared__ int lsrc[FCAP];                // 64 KB
    const int b  = blockIdx.x;
    const int lo = b << BSHIFT;
    const int hi = min(lo + BW, n);
    const int beg = row_start[lo], end = row_start[hi];
    const int cnt = end - beg;
    if (cnt <= FCAP) {
        for (int i = threadIdx.x; i < hi - lo; i += 256)
            lcur[i] = row_start[lo + i] - beg;
        __syncthreads();
        for (int j = beg + threadIdx.x; j < end; j += 256) {
            int2 e = ebuf[j];
            int pos = atomicAdd(&lcur[e.y - lo], 1);
            lsrc[pos] = e.x;
        }
        __syncthreads();
        for (int j = threadIdx.x; j < cnt; j += 256)
            sorted_src[beg + j] = lsrc[j];
    } else {                                  // safety net: direct scatter
        for (int j = beg + threadIdx.x; j < end; j += 256) {
            int2 e = ebuf[j];
            int pos = atomicAdd(&cursor[e.y], 1);
            sorted_src[pos] = e.x;
        }
    }
}

// One wave per dst node. feat is packed f16 (32 u32 words / row = 64 ch).
// Half-wave-per-edge; 4x unroll per half = 8 edges in flight (MLP).
// out[d] = dinv_d*(feat[d]*dinv_d + sum_s feat[s]*dinv_s) [+ bias].
template <bool OUT_F16, bool ADD_BIAS>
__global__ __launch_bounds__(256) void agg_f16_kernel(
    const unsigned* __restrict__ feat, const int* __restrict__ row_start,
    const int* __restrict__ sorted_src, const float* __restrict__ dinv,
    const float* __restrict__ bias, void* __restrict__ outp, int n)
{
    const int wv   = threadIdx.x >> 6;
    const int lane = threadIdx.x & 63;
    const int half = lane >> 5;
    const int lc   = lane & 31;
    const int d    = blockIdx.x * 4 + wv;
    if (d >= n) return;                 // wave-uniform exit
    const float di = dinv[d];
    float ax = 0.0f, ay = 0.0f;
    if (half == 0) {                    // self-loop term (once)
        float2 f = up2(feat[(size_t)d * 32 + lc]);
        ax = f.x * di;
        ay = f.y * di;
    }
    const int beg = row_start[d], end = row_start[d + 1];
    int i = beg + half;
    for (; i + 6 < end; i += 8) {       // 4 edges per half, batch-issued
        int s0 = sorted_src[i];
        int s1 = sorted_src[i + 2];
        int s2 = sorted_src[i + 4];
        int s3 = sorted_src[i + 6];
        float w0 = dinv[s0], w1 = dinv[s1], w2 = dinv[s2], w3 = dinv[s3];
        unsigned u0 = feat[(size_t)s0 * 32 + lc];
        unsigned u1 = feat[(size_t)s1 * 32 + lc];
        unsigned u2 = feat[(size_t)s2 * 32 + lc];
        unsigned u3 = feat[(size_t)s3 * 32 + lc];
        float2 f0 = up2(u0), f1 = up2(u1), f2 = up2(u2), f3 = up2(u3);
        ax += f0.x * w0; ay += f0.y * w0;
        ax += f1.x * w1; ay += f1.y * w1;
        ax += f2.x * w2; ay += f2.y * w2;
        ax += f3.x * w3; ay += f3.y * w3;
    }
    for (; i < end; i += 2) {           // remainder (each half strides 2)
        int s0 = sorted_src[i];
        float w0 = dinv[s0];
        float2 f0 = up2(feat[(size_t)s0 * 32 + lc]);
        ax += f0.x * w0; ay += f0.y * w0;
    }
    float ox = ax + __shfl(ax, lane + 32);
    float oy = ay + __shfl(ay, lane + 32);
    if (half == 0) {
        ox *= di; oy *= di;
        if (ADD_BIAS) {
            const float2 bv = ((const float2*)bias)[lc];
            ox += bv.x; oy += bv.y;
        }
        if (OUT_F16) ((unsigned*)outp)[(size_t)d * 32 + lc] = pk2(ox, oy);
        else         ((float2*)outp)[(size_t)d * 32 + lc] = make_float2(ox, oy);
    }
}

// r[row][c] = relu(sum_k agg_x[row][k] * W3[k][c] + b3[c]), r stored f16x2.
// 64 rows x 128 cols / block; per thread 8 cols x 4 rows (FMA-bound).
__global__ __launch_bounds__(256) void gemm1_kernel(
    const unsigned* __restrict__ xh, const float* __restrict__ W,
    const float* __restrict__ b, unsigned* __restrict__ rout, int n)
{
    __shared__ float Ws[IN_C * HID_C];   // [k][c] f32, 32 KB
    __shared__ float xs[64][IN_C + 1];   // 16.6 KB
    for (int i = threadIdx.x; i < IN_C * HID_C; i += 256) Ws[i] = W[i];
    const int r0 = blockIdx.x * 64;
    for (int i = threadIdx.x; i < 64 * 32; i += 256) {
        int row = i >> 5, c = i & 31;
        int r = r0 + row;
        float2 f = up2((r < n) ? xh[(size_t)r * 32 + c] : 0u);
        xs[row][c * 2]     = f.x;
        xs[row][c * 2 + 1] = f.y;
    }
    __syncthreads();
    const int ct = threadIdx.x & 15;   // 16 x 8 = 128 cols
    const int rt = threadIdx.x >> 4;   // 16 x 4 = 64 rows
    float acc[4][8] = {};
    const float4* Ws4 = (const float4*)Ws;
    for (int k = 0; k < IN_C; ++k) {
        float4 w0 = Ws4[k * 32 + ct * 2];
        float4 w1 = Ws4[k * 32 + ct * 2 + 1];
        #pragma unroll
        for (int ry = 0; ry < 4; ++ry) {
            float xv = xs[rt * 4 + ry][k];
            acc[ry][0] += xv * w0.x; acc[ry][1] += xv * w0.y;
            acc[ry][2] += xv * w0.z; acc[ry][3] += xv * w0.w;
            acc[ry][4] += xv * w1.x; acc[ry][5] += xv * w1.y;
            acc[ry][6] += xv * w1.z; acc[ry][7] += xv * w1.w;
        }
    }
    float4 b0 = ((const float4*)b)[ct * 2];
    float4 b1 = ((const float4*)b)[ct * 2 + 1];
    #pragma unroll
    for (int ry = 0; ry < 4; ++ry) {
        int r = r0 + rt * 4 + ry;
        if (r < n) {
            uint4 o;
            o.x = pk2(fmaxf(acc[ry][0] + b0.x, 0.0f), fmaxf(acc[ry][1] + b0.y, 0.0f));
            o.y = pk2(fmaxf(acc[ry][2] + b0.z, 0.0f), fmaxf(acc[ry][3] + b0.w, 0.0f));
            o.z = pk2(fmaxf(acc[ry][4] + b1.x, 0.0f), fmaxf(acc[ry][5] + b1.y, 0.0f));
            o.w = pk2(fmaxf(acc[ry][6] + b1.z, 0.0f), fmaxf(acc[ry][7] + b1.w, 0.0f));
            *(uint4*)&rout[(size_t)r * 64 + ct * 4] = o;
        }
    }
}

// t[row][c] = sum_k r[row][k] * W4[k][c], t stored f16x2 (into xh buffer).
// 64 rows x 64 cols / block; per thread 8 cols x 2 rows; W4 staged f16 in LDS.
__global__ __launch_bounds__(256) void gemm2_kernel(
    const unsigned* __restrict__ rin, const float* __restrict__ W,
    unsigned* __restrict__ tout, int n)
{
    __shared__ unsigned Wh[HID_C * 32];  // f16x2 [k][c/2], 16 KB
    __shared__ float xs[64][HID_C + 1];  // 33 KB
    for (int i = threadIdx.x; i < HID_C * 32; i += 256) {
        int k = i >> 5, cp = i & 31;
        Wh[i] = pk2(W[k * OUT_C + cp * 2], W[k * OUT_C + cp * 2 + 1]);
    }
    const int r0 = blockIdx.x * 64;
    for (int i = threadIdx.x; i < 64 * 64; i += 256) {
        int row = i >> 6, c = i & 63;
        int r = r0 + row;
        float2 f = up2((r < n) ? rin[(size_t)r * 64 + c] : 0u);
        xs[row][c * 2]     = f.x;
        xs[row][c * 2 + 1] = f.y;
    }
    __syncthreads();
    const int ct = threadIdx.x & 7;    // 8 x 8 = 64 cols
    const int rt = threadIdx.x >> 3;   // 32 x 2 = 64 rows
    float acc[2][8] = {};
    for (int k = 0; k < HID_C; ++k) {
        uint4 wq = *(const uint4*)&Wh[k * 32 + ct * 4];
        float2 wa = up2(wq.x), wb = up2(wq.y), wc = up2(wq.z), wd = up2(wq.w);
        #pragma unroll
        for (int ry = 0; ry < 2; ++ry) {
            float xv = xs[rt * 2 + ry][k];
            acc[ry][0] += xv * wa.x; acc[ry][1] += xv * wa.y;
            acc[ry][2] += xv * wb.x; acc[ry][3] += xv * wb.y;
            acc[ry][4] += xv * wc.x; acc[ry][5] += xv * wc.y;
            acc[ry][6] += xv * wd.x; acc[ry][7] += xv * wd.y;
        }
    }
    #pragma unroll
    for (int ry = 0; ry < 2; ++ry) {
        int r = r0 + rt * 2 + ry;
        if (r < n) {
            uint4 o;
            o.x = pk2(acc[ry][0], acc[ry][1]);
            o.y = pk2(acc[ry][2], acc[ry][3]);
            o.z = pk2(acc[ry][4], acc[ry][5]);
            o.w = pk2(acc[ry][6], acc[ry][7]);
            *(uint4*)&tout[(size_t)r * 32 + ct * 4] = o;
        }
    }
}

extern "C" void kernel_launch(void* const* d_in, const int* in_sizes, int n_in,
                              void* d_out, int out_size, void* d_ws, size_t ws_size,
                              hipStream_t stream)
{
    const float* x  = (const float*)d_in[0];
    const int*   ei = (const int*)d_in[1];
    const float* W3 = (const float*)d_in[2];
    const float* b3 = (const float*)d_in[3];
    const float* W4 = (const float*)d_in[4];
    const float* b4 = (const float*)d_in[5];
    float* out = (float*)d_out;

    const int n = in_sizes[0] / IN_C;   // 100000
    const int E = in_sizes[1] / 2;      // 1600000
    const int* src = ei;
    const int* dst = ei + E;
    const int nbkt = (n + BW - 1) >> BSHIFT;   // 196

    const size_t n_pad = ((size_t)n + 256) & ~(size_t)255;  // room for row_start[n]

    // Workspace: cnt | row_start | cursor | partials(512) | bcur(256) | dinv |
    //            ssrc | ebuf (E int2) | xh (n*32 u32, reused as t) |
    //            agg_x (n*32 u32) | r (n*64 u32)
    int*      cnt       = (int*)d_ws;
    int*      row_start = cnt + n_pad;
    int*      cursor    = row_start + n_pad;
    int*      partials  = cursor + n_pad;
    int*      bcur      = partials + 512;
    float*    dinv      = (float*)(bcur + 256);
    int*      ssrc      = (int*)(dinv + n_pad);
    int2*     ebuf      = (int2*)(ssrc + (((size_t)E + 255) & ~(size_t)255));
    unsigned* xh        = (unsigned*)(ebuf + (size_t)E);
    unsigned* agg_x     = xh + n_pad * 32;
    unsigned* r         = agg_x + n_pad * 32;
    unsigned* t         = xh;                      // xh dead after agg1

    const int nb  = (n + 255) / 256;   // 391
    const int neb = (E + 255) / 256;

    cvt_kernel<<<(n * 32 + 255) / 256, 256, 0, stream>>>(
        (const float2*)x, xh, n * 32);

    zero_cnt_kernel<<<nb, 256, 0, stream>>>(cnt, n);
    hist_kernel<<<neb, 256, 0, stream>>>(dst, cnt, E);
    scan1_kernel<<<nb, 256, 0, stream>>>(cnt, row_start, partials, n);
    scan2_kernel<<<1, 512, 0, stream>>>(partials, nb);
    scan3_kernel<<<nb, 256, 0, stream>>>(cnt, row_start, partials, cursor,
                                         dinv, bcur, n, E);

    bin_kernel<<<(E + TILE - 1) / TILE, 256, 0, stream>>>(src, dst, bcur, ebuf, E, nbkt);
    fill3_kernel<<<nbkt, 256, 0, stream>>>(ebuf, row_start, cursor, ssrc, n);

    agg_f16_kernel<true, false><<<(n + 3) / 4, 256, 0, stream>>>(
        xh, row_start, ssrc, dinv, nullptr, agg_x, n);

    gemm1_kernel<<<(n + 63) / 64, 256, 0, stream>>>(agg_x, W3, b3, r, n);
    gemm2_kernel<<<(n + 63) / 64, 256, 0, stream>>>(r, W4, t, n);

    agg_f16_kernel<false, true><<<(n + 3) / 4, 256, 0, stream>>>(
        t, row_start, ssrc, dinv, b4, out, n);
}

// Round 9
// 336.899 us; speedup vs baseline: 1.2954x; 1.1520x over previous
//
#include <hip/hip_runtime.h>
#include <hip/hip_bf16.h>
#include <hip/hip_fp16.h>

// GCNDecoder: 2-layer GCN, N=100000, E=1600000, 64 -> 128 -> 64, fp32.
//
// R1: agg-before-GEMM (linearity), dst-CSR + gather agg (no fp32 atomics).
// R2/R4/R6/R7: scatter lesson: workgroup->XCD placement is NOT controllable;
//   random global 4B stores/atomics from 8 non-coherent L2s write ~32-64B
//   sectors to HBM (~10x amplification). Fix = all random placement in LDS,
//   HBM writes strictly coalesced (R7 fill3: WRITE collapsed, -48 us).
// R3/R5: f16 gather features; agg 8-edge MLP unroll; no-nt-on-reused-lines.
// R8: hist_kernel was the last random-atomic kernel (65 us, WRITE=50 MB for
//   a 400 KB counter array: ~31 B HBM write per device-scope atomic). Killed
//   the per-node global hist entirely: bhist does per-block LDS histogram
//   over 196 BUCKETS only (one 196-atomic flush/block); bucket_kernel fuses
//   per-node count + scan + row_start/dinv emit + LDS-cursor placement +
//   coalesced sorted_src flush, one block per bucket. No per-node global
//   atomics remain anywhere.
//
// Pipeline:
//   cvt(x->xh f16) -> zero_small -> bhist(196 LDS hist) -> bscan
//   -> bin(ebuf, 196 buckets) -> bucket(row_start+dinv+sorted_src)
//   -> agg(xh -> agg_x f16) -> gemm1 (r = relu(agg_x W3 + b3), f16)
//   -> gemm2 (t = r W4, f16) -> agg(t -> out f32, +b4)

constexpr int IN_C  = 64;
constexpr int HID_C = 128;
constexpr int OUT_C = 64;
constexpr int BSHIFT = 9;                 // bucket width = 512 dst nodes
constexpr int BW     = 1 << BSHIFT;
constexpr int TILE   = 4096;              // bin tile (edges)
constexpr int FCAP   = 16384;             // bucket LDS region cap (64 KB)

__device__ __forceinline__ float2 up2(unsigned u) {      // unpack f16x2
    __half2 h = *reinterpret_cast<__half2*>(&u);
    return __half22float2(h);
}
__device__ __forceinline__ unsigned pk2(float a, float b) {  // pack f16x2
    __half2 h = __float22half2_rn(make_float2(a, b));
    return *reinterpret_cast<unsigned*>(&h);
}

// Pack 2 consecutive fp32 channels into one u32 of f16 pairs.
__global__ __launch_bounds__(256) void cvt_kernel(
    const float2* __restrict__ in, unsigned* __restrict__ outw, int nw)
{
    int i = blockIdx.x * 256 + threadIdx.x;
    if (i < nw) {
        float2 v = in[i];
        outw[i] = pk2(v.x, v.y);
    }
}

__global__ __launch_bounds__(256) void zero_small_kernel(int* __restrict__ p, int m)
{
    int i = blockIdx.x * 256 + threadIdx.x;
    if (i < m) p[i] = 0;
}

// Per-block LDS histogram over buckets (d>>9); one global flush of nbkt
// atomics per block (256 blocks x 196 words -> negligible HBM traffic).
__global__ __launch_bounds__(256) void bhist_kernel(
    const int* __restrict__ dst, int* __restrict__ bcnt, int E, int nbkt)
{
    __shared__ int h[256];
    h[threadIdx.x] = 0;
    __syncthreads();
    const int stride = gridDim.x * 256;
    for (int e = blockIdx.x * 256 + threadIdx.x; e < E; e += stride) {
        int d = __builtin_nontemporal_load(&dst[e]);
        atomicAdd(&h[d >> BSHIFT], 1);
    }
    __syncthreads();
    if (threadIdx.x < nbkt && h[threadIdx.x] != 0)
        atomicAdd(&bcnt[threadIdx.x], h[threadIdx.x]);
}

// Single-block exclusive scan of bcnt[nbkt] -> bbase[nbkt+1]; bcur=bbase.
__global__ __launch_bounds__(256) void bscan_kernel(
    const int* __restrict__ bcnt, int* __restrict__ bbase,
    int* __restrict__ bcur, int nbkt)
{
    __shared__ int s[256];
    int v = (threadIdx.x < nbkt) ? bcnt[threadIdx.x] : 0;
    s[threadIdx.x] = v;
    __syncthreads();
    for (int off = 1; off < 256; off <<= 1) {
        int t = (threadIdx.x >= off) ? s[threadIdx.x - off] : 0;
        __syncthreads();
        s[threadIdx.x] += t;
        __syncthreads();
    }
    if (threadIdx.x < nbkt) {
        int ex = s[threadIdx.x] - v;
        bbase[threadIdx.x] = ex;
        bcur[threadIdx.x]  = ex;
        if (threadIdx.x == nbkt - 1) bbase[nbkt] = s[threadIdx.x];
    }
}

// Bin (src,dst) into nbkt contiguous per-bucket regions of ebuf. Two LDS
// stages (raw -> bucket-grouped); flush coalesced (~21 edges/bucket/tile).
__global__ __launch_bounds__(256) void bin_kernel(
    const int* __restrict__ src, const int* __restrict__ dst,
    int* __restrict__ bcur, int2* __restrict__ ebuf, int E, int nbkt)
{
    __shared__ int2 stageR[TILE];             // 32 KB raw
    __shared__ int2 stageS[TILE];             // 32 KB bucket-grouped
    __shared__ int lcnt[256], lofs[256], lpos[256], gbase[256];
    const int base = blockIdx.x * TILE;
    const int cnt_mine = min(TILE, E - base);
    for (int b = threadIdx.x; b < nbkt; b += 256) lcnt[b] = 0;
    __syncthreads();
    for (int jo = threadIdx.x; jo < cnt_mine; jo += 256) {
        int s = __builtin_nontemporal_load(&src[base + jo]);
        int d = __builtin_nontemporal_load(&dst[base + jo]);
        stageR[jo] = make_int2(s, d);
        atomicAdd(&lcnt[d >> BSHIFT], 1);
    }
    __syncthreads();
    if (threadIdx.x == 0) {                   // serial prefix over nbkt buckets
        int acc = 0;
        for (int b = 0; b < nbkt; ++b) { lofs[b] = acc; lpos[b] = acc; acc += lcnt[b]; }
    }
    __syncthreads();
    if (threadIdx.x < nbkt)
        gbase[threadIdx.x] = atomicAdd(&bcur[threadIdx.x], lcnt[threadIdx.x]);
    for (int jo = threadIdx.x; jo < cnt_mine; jo += 256) {
        int2 e = stageR[jo];
        int pos = atomicAdd(&lpos[e.y >> BSHIFT], 1);
        stageS[pos] = e;
    }
    __syncthreads();
    for (int j = threadIdx.x; j < cnt_mine; j += 256) {
        int2 e = stageS[j];
        int b = e.y >> BSHIFT;
        ebuf[gbase[b] + (j - lofs[b])] = e;
    }
}

// One block per bucket: per-node LDS histogram of the bucket's ebuf region,
// LDS exclusive scan (512 wide), coalesced row_start+dinv emit, LDS-cursor
// placement into lsrc, coalesced sorted_src flush. No global atomics.
__global__ __launch_bounds__(256) void bucket_kernel(
    const int2* __restrict__ ebuf, const int* __restrict__ bbase,
    int* __restrict__ row_start, float* __restrict__ dinv,
    int* __restrict__ sorted_src, int n, int E, int nbkt)
{
    __shared__ int lcnt[BW];                  // per-node counts
    __shared__ int lcur[BW];                  // exclusive offsets -> cursors
    __shared__ int s[256];                    // block scan workspace
    __shared__ int lsrc[FCAP];                // 64 KB staging
    const int b   = blockIdx.x;
    const int lo  = b << BSHIFT;
    const int hi  = min(lo + BW, n);
    const int nn  = hi - lo;
    const int beg = bbase[b], end = bbase[b + 1];
    const int cnt = end - beg;
    const int t   = threadIdx.x;
    for (int i = t; i < nn; i += 256) lcnt[i] = 0;
    __syncthreads();
    for (int j = beg + t; j < end; j += 256)
        atomicAdd(&lcnt[ebuf[j].y - lo], 1);
    __syncthreads();
    // exclusive scan over nn (<=512): thread t owns elements 2t, 2t+1
    int a0 = (2 * t     < nn) ? lcnt[2 * t]     : 0;
    int a1 = (2 * t + 1 < nn) ? lcnt[2 * t + 1] : 0;
    int tsum = a0 + a1;
    s[t] = tsum;
    __syncthreads();
    for (int off = 1; off < 256; off <<= 1) {
        int v = (t >= off) ? s[t - off] : 0;
        __syncthreads();
        s[t] += v;
        __syncthreads();
    }
    int texcl = s[t] - tsum;
    if (2 * t < nn) {
        lcur[2 * t] = texcl;
        row_start[lo + 2 * t] = beg + texcl;
        dinv[lo + 2 * t] = rsqrtf((float)a0 + 1.0f);
    }
    if (2 * t + 1 < nn) {
        lcur[2 * t + 1] = texcl + a0;
        row_start[lo + 2 * t + 1] = beg + texcl + a0;
        dinv[lo + 2 * t + 1] = rsqrtf((float)a1 + 1.0f);
    }
    if (t == 0 && b == nbkt - 1) row_start[n] = E;
    __syncthreads();
    if (cnt <= FCAP) {
        for (int j = beg + t; j < end; j += 256) {
            int2 e = ebuf[j];
            int pos = atomicAdd(&lcur[e.y - lo], 1);
            lsrc[pos] = e.x;
        }
        __syncthreads();
        for (int j = t; j < cnt; j += 256)
            sorted_src[beg + j] = lsrc[j];
    } else {                                  // safety net (never on this graph)
        for (int j = beg + t; j < end; j += 256) {
            int2 e = ebuf[j];
            int pos = atomicAdd(&lcur[e.y - lo], 1);
            sorted_src[beg + pos] = e.x;
        }
    }
}

// One wave per dst node. feat is packed f16 (32 u32 words / row = 64 ch).
// Half-wave-per-edge; 4x unroll per half = 8 edges in flight (MLP).
// out[d] = dinv_d*(feat[d]*dinv_d + sum_s feat[s]*dinv_s) [+ bias].
template <bool OUT_F16, bool ADD_BIAS>
__global__ __launch_bounds__(256) void agg_f16_kernel(
    const unsigned* __restrict__ feat, const int* __restrict__ row_start,
    const int* __restrict__ sorted_src, const float* __restrict__ dinv,
    const float* __restrict__ bias, void* __restrict__ outp, int n)
{
    const int wv   = threadIdx.x >> 6;
    const int lane = threadIdx.x & 63;
    const int half = lane >> 5;
    const int lc   = lane & 31;
    const int d    = blockIdx.x * 4 + wv;
    if (d >= n) return;                 // wave-uniform exit
    const float di = dinv[d];
    float ax = 0.0f, ay = 0.0f;
    if (half == 0) {                    // self-loop term (once)
        float2 f = up2(feat[(size_t)d * 32 + lc]);
        ax = f.x * di;
        ay = f.y * di;
    }
    const int beg = row_start[d], end = row_start[d + 1];
    int i = beg + half;
    for (; i + 6 < end; i += 8) {       // 4 edges per half, batch-issued
        int s0 = sorted_src[i];
        int s1 = sorted_src[i + 2];
        int s2 = sorted_src[i + 4];
        int s3 = sorted_src[i + 6];
        float w0 = dinv[s0], w1 = dinv[s1], w2 = dinv[s2], w3 = dinv[s3];
        unsigned u0 = feat[(size_t)s0 * 32 + lc];
        unsigned u1 = feat[(size_t)s1 * 32 + lc];
        unsigned u2 = feat[(size_t)s2 * 32 + lc];
        unsigned u3 = feat[(size_t)s3 * 32 + lc];
        float2 f0 = up2(u0), f1 = up2(u1), f2 = up2(u2), f3 = up2(u3);
        ax += f0.x * w0; ay += f0.y * w0;
        ax += f1.x * w1; ay += f1.y * w1;
        ax += f2.x * w2; ay += f2.y * w2;
        ax += f3.x * w3; ay += f3.y * w3;
    }
    for (; i < end; i += 2) {           // remainder (each half strides 2)
        int s0 = sorted_src[i];
        float w0 = dinv[s0];
        float2 f0 = up2(feat[(size_t)s0 * 32 + lc]);
        ax += f0.x * w0; ay += f0.y * w0;
    }
    float ox = ax + __shfl(ax, lane + 32);
    float oy = ay + __shfl(ay, lane + 32);
    if (half == 0) {
        ox *= di; oy *= di;
        if (ADD_BIAS) {
            const float2 bv = ((const float2*)bias)[lc];
            ox += bv.x; oy += bv.y;
        }
        if (OUT_F16) ((unsigned*)outp)[(size_t)d * 32 + lc] = pk2(ox, oy);
        else         ((float2*)outp)[(size_t)d * 32 + lc] = make_float2(ox, oy);
    }
}

// r[row][c] = relu(sum_k agg_x[row][k] * W3[k][c] + b3[c]), r stored f16x2.
// 64 rows x 128 cols / block; per thread 8 cols x 4 rows (FMA-bound).
__global__ __launch_bounds__(256) void gemm1_kernel(
    const unsigned* __restrict__ xh, const float* __restrict__ W,
    const float* __restrict__ b, unsigned* __restrict__ rout, int n)
{
    __shared__ float Ws[IN_C * HID_C];   // [k][c] f32, 32 KB
    __shared__ float xs[64][IN_C + 1];   // 16.6 KB
    for (int i = threadIdx.x; i < IN_C * HID_C; i += 256) Ws[i] = W[i];
    const int r0 = blockIdx.x * 64;
    for (int i = threadIdx.x; i < 64 * 32; i += 256) {
        int row = i >> 5, c = i & 31;
        int r = r0 + row;
        float2 f = up2((r < n) ? xh[(size_t)r * 32 + c] : 0u);
        xs[row][c * 2]     = f.x;
        xs[row][c * 2 + 1] = f.y;
    }
    __syncthreads();
    const int ct = threadIdx.x & 15;   // 16 x 8 = 128 cols
    const int rt = threadIdx.x >> 4;   // 16 x 4 = 64 rows
    float acc[4][8] = {};
    const float4* Ws4 = (const float4*)Ws;
    for (int k = 0; k < IN_C; ++k) {
        float4 w0 = Ws4[k * 32 + ct * 2];
        float4 w1 = Ws4[k * 32 + ct * 2 + 1];
        #pragma unroll
        for (int ry = 0; ry < 4; ++ry) {
            float xv = xs[rt * 4 + ry][k];
            acc[ry][0] += xv * w0.x; acc[ry][1] += xv * w0.y;
            acc[ry][2] += xv * w0.z; acc[ry][3] += xv * w0.w;
            acc[ry][4] += xv * w1.x; acc[ry][5] += xv * w1.y;
            acc[ry][6] += xv * w1.z; acc[ry][7] += xv * w1.w;
        }
    }
    float4 b0 = ((const float4*)b)[ct * 2];
    float4 b1 = ((const float4*)b)[ct * 2 + 1];
    #pragma unroll
    for (int ry = 0; ry < 4; ++ry) {
        int r = r0 + rt * 4 + ry;
        if (r < n) {
            uint4 o;
            o.x = pk2(fmaxf(acc[ry][0] + b0.x, 0.0f), fmaxf(acc[ry][1] + b0.y, 0.0f));
            o.y = pk2(fmaxf(acc[ry][2] + b0.z, 0.0f), fmaxf(acc[ry][3] + b0.w, 0.0f));
            o.z = pk2(fmaxf(acc[ry][4] + b1.x, 0.0f), fmaxf(acc[ry][5] + b1.y, 0.0f));
            o.w = pk2(fmaxf(acc[ry][6] + b1.z, 0.0f), fmaxf(acc[ry][7] + b1.w, 0.0f));
            *(uint4*)&rout[(size_t)r * 64 + ct * 4] = o;
        }
    }
}

// t[row][c] = sum_k r[row][k] * W4[k][c], t stored f16x2 (into xh buffer).
// 64 rows x 64 cols / block; per thread 8 cols x 2 rows; W4 staged f16 in LDS.
__global__ __launch_bounds__(256) void gemm2_kernel(
    const unsigned* __restrict__ rin, const float* __restrict__ W,
    unsigned* __restrict__ tout, int n)
{
    __shared__ unsigned Wh[HID_C * 32];  // f16x2 [k][c/2], 16 KB
    __shared__ float xs[64][HID_C + 1];  // 33 KB
    for (int i = threadIdx.x; i < HID_C * 32; i += 256) {
        int k = i >> 5, cp = i & 31;
        Wh[i] = pk2(W[k * OUT_C + cp * 2], W[k * OUT_C + cp * 2 + 1]);
    }
    const int r0 = blockIdx.x * 64;
    for (int i = threadIdx.x; i < 64 * 64; i += 256) {
        int row = i >> 6, c = i & 63;
        int r = r0 + row;
        float2 f = up2((r < n) ? rin[(size_t)r * 64 + c] : 0u);
        xs[row][c * 2]     = f.x;
        xs[row][c * 2 + 1] = f.y;
    }
    __syncthreads();
    const int ct = threadIdx.x & 7;    // 8 x 8 = 64 cols
    const int rt = threadIdx.x >> 3;   // 32 x 2 = 64 rows
    float acc[2][8] = {};
    for (int k = 0; k < HID_C; ++k) {
        uint4 wq = *(const uint4*)&Wh[k * 32 + ct * 4];
        float2 wa = up2(wq.x), wb = up2(wq.y), wc = up2(wq.z), wd = up2(wq.w);
        #pragma unroll
        for (int ry = 0; ry < 2; ++ry) {
            float xv = xs[rt * 2 + ry][k];
            acc[ry][0] += xv * wa.x; acc[ry][1] += xv * wa.y;
            acc[ry][2] += xv * wb.x; acc[ry][3] += xv * wb.y;
            acc[ry][4] += xv * wc.x; acc[ry][5] += xv * wc.y;
            acc[ry][6] += xv * wd.x; acc[ry][7] += xv * wd.y;
        }
    }
    #pragma unroll
    for (int ry = 0; ry < 2; ++ry) {
        int r = r0 + rt * 2 + ry;
        if (r < n) {
            uint4 o;
            o.x = pk2(acc[ry][0], acc[ry][1]);
            o.y = pk2(acc[ry][2], acc[ry][3]);
            o.z = pk2(acc[ry][4], acc[ry][5]);
            o.w = pk2(acc[ry][6], acc[ry][7]);
            *(uint4*)&tout[(size_t)r * 32 + ct * 4] = o;
        }
    }
}

extern "C" void kernel_launch(void* const* d_in, const int* in_sizes, int n_in,
                              void* d_out, int out_size, void* d_ws, size_t ws_size,
                              hipStream_t stream)
{
    const float* x  = (const float*)d_in[0];
    const int*   ei = (const int*)d_in[1];
    const float* W3 = (const float*)d_in[2];
    const float* b3 = (const float*)d_in[3];
    const float* W4 = (const float*)d_in[4];
    const float* b4 = (const float*)d_in[5];
    float* out = (float*)d_out;

    const int n = in_sizes[0] / IN_C;   // 100000
    const int E = in_sizes[1] / 2;      // 1600000
    const int* src = ei;
    const int* dst = ei + E;
    const int nbkt = (n + BW - 1) >> BSHIFT;   // 196

    const size_t n_pad = ((size_t)n + 256) & ~(size_t)255;  // room for row_start[n]

    // Workspace: bcnt(256) | bbase(512) | bcur(256) | row_start | dinv |
    //            ssrc | ebuf (E int2) | xh (n*32 u32, reused as t) |
    //            agg_x (n*32 u32) | r (n*64 u32)
    int*      bcnt      = (int*)d_ws;
    int*      bbase     = bcnt + 256;
    int*      bcur      = bbase + 512;
    int*      row_start = bcur + 256;
    float*    dinv      = (float*)(row_start + n_pad);
    int*      ssrc      = (int*)(dinv + n_pad);
    int2*     ebuf      = (int2*)(ssrc + (((size_t)E + 255) & ~(size_t)255));
    unsigned* xh        = (unsigned*)(ebuf + (size_t)E);
    unsigned* agg_x     = xh + n_pad * 32;
    unsigned* r         = agg_x + n_pad * 32;
    unsigned* t         = xh;                      // xh dead after agg1

    cvt_kernel<<<(n * 32 + 255) / 256, 256, 0, stream>>>(
        (const float2*)x, xh, n * 32);

    zero_small_kernel<<<1, 256, 0, stream>>>(bcnt, 256);
    bhist_kernel<<<256, 256, 0, stream>>>(dst, bcnt, E, nbkt);
    bscan_kernel<<<1, 256, 0, stream>>>(bcnt, bbase, bcur, nbkt);

    bin_kernel<<<(E + TILE - 1) / TILE, 256, 0, stream>>>(src, dst, bcur, ebuf, E, nbkt);
    bucket_kernel<<<nbkt, 256, 0, stream>>>(ebuf, bbase, row_start, dinv, ssrc, n, E, nbkt);

    agg_f16_kernel<true, false><<<(n + 3) / 4, 256, 0, stream>>>(
        xh, row_start, ssrc, dinv, nullptr, agg_x, n);

    gemm1_kernel<<<(n + 63) / 64, 256, 0, stream>>>(agg_x, W3, b3, r, n);
    gemm2_kernel<<<(n + 63) / 64, 256, 0, stream>>>(r, W4, t, n);

    agg_f16_kernel<false, true><<<(n + 3) / 4, 256, 0, stream>>>(
        t, row_start, ssrc, dinv, b4, out, n);
}

// Round 10
// 328.056 us; speedup vs baseline: 1.3304x; 1.0270x over previous
//
#include <hip/hip_runtime.h>
#include <hip/hip_bf16.h>
#include <hip/hip_fp16.h>

// GCNDecoder: 2-layer GCN, N=100000, E=1600000, 64 -> 128 -> 64, fp32.
//
// R1: agg-before-GEMM (linearity), dst-CSR + gather agg (no fp32 atomics).
// R2-R8 scatter lesson: workgroup->XCD placement is NOT controllable; any
//   random global 4B store/atomic costs ~32-64B HBM write (8 non-coherent
//   L2s). Fix = all random placement in LDS, HBM strictly coalesced. R8
//   removed the last per-node global atomics (hist): 388 -> 337 us.
// R3/R5: f16 gather features; agg 8-edge MLP unroll; no nt on reused lines.
// R9: (a) ebuf packed int2 -> u32 (src<<9 | dst&511): halves bin write +
//   bucket read; bin keeps edges in registers, parallel 256-wide bucket scan.
//   (b) dinv pre-scaled into f16 features (cvt runs AFTER bucket; gemm2
//   scales its output rows by dinv[r]): removes the random dinv[s] gather
//   from agg's dependent chain. (c) agg prefetches next batch's indices
//   while current feat gathers are in flight.
//   agg FETCH 89.8 MB vs ~20 MB compulsory = 8-XCD gather redundancy at the
//   f16 floor; if agg dur doesn't move this round it is fabric-bound-done.
//
// Pipeline:
//   zero_small -> bhist(196 LDS hist) -> bscan -> bin(ebuf u32)
//   -> bucket(row_start+dinv+sorted_src, all LDS-staged)
//   -> cvt(x*dinv -> xh f16) -> agg(xh -> agg_x f16)
//   -> gemm1 (r = relu(agg_x W3 + b3), f16) -> gemm2 (t = (r W4)*dinv, f16)
//   -> agg(t -> out f32, +b4)

constexpr int IN_C  = 64;
constexpr int HID_C = 128;
constexpr int OUT_C = 64;
constexpr int BSHIFT = 9;                 // bucket width = 512 dst nodes
constexpr int BW     = 1 << BSHIFT;
constexpr int TILE   = 4096;              // bin tile (16 edges/thread)
constexpr int FCAP   = 16384;             // bucket LDS region cap (64 KB)

__device__ __forceinline__ float2 up2(unsigned u) {      // unpack f16x2
    __half2 h = *reinterpret_cast<__half2*>(&u);
    return __half22float2(h);
}
__device__ __forceinline__ unsigned pk2(float a, float b) {  // pack f16x2
    __half2 h = __float22half2_rn(make_float2(a, b));
    return *reinterpret_cast<unsigned*>(&h);
}

__global__ __launch_bounds__(256) void zero_small_kernel(int* __restrict__ p, int m)
{
    int i = blockIdx.x * 256 + threadIdx.x;
    if (i < m) p[i] = 0;
}

// Per-block LDS histogram over buckets (d>>9); one nbkt-atomic flush/block.
__global__ __launch_bounds__(256) void bhist_kernel(
    const int* __restrict__ dst, int* __restrict__ bcnt, int E, int nbkt)
{
    __shared__ int h[256];
    h[threadIdx.x] = 0;
    __syncthreads();
    const int stride = gridDim.x * 256;
    for (int e = blockIdx.x * 256 + threadIdx.x; e < E; e += stride) {
        int d = __builtin_nontemporal_load(&dst[e]);
        atomicAdd(&h[d >> BSHIFT], 1);
    }
    __syncthreads();
    if (threadIdx.x < nbkt && h[threadIdx.x] != 0)
        atomicAdd(&bcnt[threadIdx.x], h[threadIdx.x]);
}

// Single-block exclusive scan of bcnt[nbkt] -> bbase[nbkt+1]; bcur=bbase.
__global__ __launch_bounds__(256) void bscan_kernel(
    const int* __restrict__ bcnt, int* __restrict__ bbase,
    int* __restrict__ bcur, int nbkt)
{
    __shared__ int s[256];
    int v = (threadIdx.x < nbkt) ? bcnt[threadIdx.x] : 0;
    s[threadIdx.x] = v;
    __syncthreads();
    for (int off = 1; off < 256; off <<= 1) {
        int t = (threadIdx.x >= off) ? s[threadIdx.x - off] : 0;
        __syncthreads();
        s[threadIdx.x] += t;
        __syncthreads();
    }
    if (threadIdx.x < nbkt) {
        int ex = s[threadIdx.x] - v;
        bbase[threadIdx.x] = ex;
        bcur[threadIdx.x]  = ex;
        if (threadIdx.x == nbkt - 1) bbase[nbkt] = s[threadIdx.x];
    }
}

// Bin edges into nbkt contiguous regions of ebuf, PACKED u32 per edge:
// w = (src << 9) | (dst & 511). Edges live in registers (16/thread);
// bucket-grouped via LDS; flush coalesced. Parallel 256-wide scan.
__global__ __launch_bounds__(256) void bin_kernel(
    const int* __restrict__ src, const int* __restrict__ dst,
    int* __restrict__ bcur, unsigned* __restrict__ ebuf, int E, int nbkt)
{
    __shared__ unsigned stageS[TILE];           // 16 KB bucket-grouped
    __shared__ unsigned char stageB[TILE];      // 4 KB bucket ids
    __shared__ int lcnt[256], lofs[256], lpos[256], gbase[256], s[256];
    const int base = blockIdx.x * TILE;
    const int cnt_mine = min(TILE, E - base);
    const int t = threadIdx.x;
    lcnt[t] = 0;
    __syncthreads();
    unsigned w[16]; int p[16];
    #pragma unroll
    for (int k = 0; k < 16; ++k) {
        int jo = t + k * 256;
        if (jo < cnt_mine) {
            int sv = __builtin_nontemporal_load(&src[base + jo]);
            int dv = __builtin_nontemporal_load(&dst[base + jo]);
            p[k] = dv >> BSHIFT;
            w[k] = ((unsigned)sv << BSHIFT) | (unsigned)(dv & (BW - 1));
            atomicAdd(&lcnt[p[k]], 1);
        } else p[k] = -1;
    }
    __syncthreads();
    int v = lcnt[t];                             // parallel exclusive scan
    s[t] = v;
    __syncthreads();
    for (int off = 1; off < 256; off <<= 1) {
        int u = (t >= off) ? s[t - off] : 0;
        __syncthreads();
        s[t] += u;
        __syncthreads();
    }
    lofs[t] = s[t] - v;
    lpos[t] = s[t] - v;
    if (t < nbkt && v != 0) gbase[t] = atomicAdd(&bcur[t], v);
    __syncthreads();
    #pragma unroll
    for (int k = 0; k < 16; ++k) {
        if (p[k] >= 0) {
            int pos = atomicAdd(&lpos[p[k]], 1);
            stageS[pos] = w[k];
            stageB[pos] = (unsigned char)p[k];
        }
    }
    __syncthreads();
    for (int j = t; j < cnt_mine; j += 256) {
        int b = stageB[j];
        ebuf[gbase[b] + (j - lofs[b])] = stageS[j];
    }
}

// One block per bucket: per-node LDS hist of the region, LDS scan (512),
// coalesced row_start+dinv emit, LDS-cursor placement, coalesced flush.
__global__ __launch_bounds__(256) void bucket_kernel(
    const unsigned* __restrict__ ebuf, const int* __restrict__ bbase,
    int* __restrict__ row_start, float* __restrict__ dinv,
    int* __restrict__ sorted_src, int n, int E, int nbkt)
{
    __shared__ int lcnt[BW];
    __shared__ int lcur[BW];
    __shared__ int s[256];
    __shared__ int lsrc[FCAP];                // 64 KB staging
    const int b   = blockIdx.x;
    const int lo  = b << BSHIFT;
    const int hi  = min(lo + BW, n);
    const int nn  = hi - lo;
    const int beg = bbase[b], end = bbase[b + 1];
    const int cnt = end - beg;
    const int t   = threadIdx.x;
    for (int i = t; i < nn; i += 256) lcnt[i] = 0;
    __syncthreads();
    for (int j = beg + t; j < end; j += 256)
        atomicAdd(&lcnt[ebuf[j] & (BW - 1)], 1);
    __syncthreads();
    int a0 = (2 * t     < nn) ? lcnt[2 * t]     : 0;
    int a1 = (2 * t + 1 < nn) ? lcnt[2 * t + 1] : 0;
    int tsum = a0 + a1;
    s[t] = tsum;
    __syncthreads();
    for (int off = 1; off < 256; off <<= 1) {
        int v = (t >= off) ? s[t - off] : 0;
        __syncthreads();
        s[t] += v;
        __syncthreads();
    }
    int texcl = s[t] - tsum;
    if (2 * t < nn) {
        lcur[2 * t] = texcl;
        row_start[lo + 2 * t] = beg + texcl;
        dinv[lo + 2 * t] = rsqrtf((float)a0 + 1.0f);
    }
    if (2 * t + 1 < nn) {
        lcur[2 * t + 1] = texcl + a0;
        row_start[lo + 2 * t + 1] = beg + texcl + a0;
        dinv[lo + 2 * t + 1] = rsqrtf((float)a1 + 1.0f);
    }
    if (t == 0 && b == nbkt - 1) row_start[n] = E;
    __syncthreads();
    if (cnt <= FCAP) {
        for (int j = beg + t; j < end; j += 256) {
            unsigned w = ebuf[j];
            int pos = atomicAdd(&lcur[w & (BW - 1)], 1);
            lsrc[pos] = (int)(w >> BSHIFT);
        }
        __syncthreads();
        for (int j = t; j < cnt; j += 256)
            sorted_src[beg + j] = lsrc[j];
    } else {                                  // safety net (never on this graph)
        for (int j = beg + t; j < end; j += 256) {
            unsigned w = ebuf[j];
            int pos = atomicAdd(&lcur[w & (BW - 1)], 1);
            sorted_src[beg + pos] = (int)(w >> BSHIFT);
        }
    }
}

// Pack 2 fp32 channels into f16x2, PRE-SCALED by dinv[row] (row = i>>5).
__global__ __launch_bounds__(256) void cvt_scaled_kernel(
    const float2* __restrict__ in, const float* __restrict__ dinv,
    unsigned* __restrict__ outw, int nw)
{
    int i = blockIdx.x * 256 + threadIdx.x;
    if (i < nw) {
        float2 v = in[i];
        float dv = dinv[i >> 5];
        outw[i] = pk2(v.x * dv, v.y * dv);
    }
}

// One wave per dst node. feat is packed f16, PRE-SCALED by dinv[src].
// Half-wave-per-edge, 4 edges per half in flight; next batch's indices are
// prefetched while current gathers are outstanding.
// out[d] = dinv_d * (feat'[d] + sum_s feat'[s]) [+ bias].
template <bool OUT_F16, bool ADD_BIAS>
__global__ __launch_bounds__(256) void agg_f16_kernel(
    const unsigned* __restrict__ feat, const int* __restrict__ row_start,
    const int* __restrict__ sorted_src, const float* __restrict__ dinv,
    const float* __restrict__ bias, void* __restrict__ outp, int n)
{
    const int wv   = threadIdx.x >> 6;
    const int lane = threadIdx.x & 63;
    const int half = lane >> 5;
    const int lc   = lane & 31;
    const int d    = blockIdx.x * 4 + wv;
    if (d >= n) return;                 // wave-uniform exit
    const float di = dinv[d];
    float ax = 0.0f, ay = 0.0f;
    if (half == 0) {                    // self-loop term (feat already scaled)
        float2 f = up2(feat[(size_t)d * 32 + lc]);
        ax = f.x;
        ay = f.y;
    }
    const int beg = row_start[d], end = row_start[d + 1];
    int i = beg + half;
    int s0, s1, s2, s3;
    if (i + 6 < end) {
        s0 = sorted_src[i]; s1 = sorted_src[i + 2];
        s2 = sorted_src[i + 4]; s3 = sorted_src[i + 6];
    }
    while (i + 6 < end) {
        unsigned u0 = feat[(size_t)s0 * 32 + lc];
        unsigned u1 = feat[(size_t)s1 * 32 + lc];
        unsigned u2 = feat[(size_t)s2 * 32 + lc];
        unsigned u3 = feat[(size_t)s3 * 32 + lc];
        int ni = i + 8;
        if (ni + 6 < end) {             // prefetch next batch's indices
            s0 = sorted_src[ni]; s1 = sorted_src[ni + 2];
            s2 = sorted_src[ni + 4]; s3 = sorted_src[ni + 6];
        }
        float2 f0 = up2(u0), f1 = up2(u1), f2 = up2(u2), f3 = up2(u3);
        ax += f0.x; ay += f0.y;
        ax += f1.x; ay += f1.y;
        ax += f2.x; ay += f2.y;
        ax += f3.x; ay += f3.y;
        i = ni;
    }
    for (; i < end; i += 2) {           // remainder (each half strides 2)
        float2 f0 = up2(feat[(size_t)sorted_src[i] * 32 + lc]);
        ax += f0.x; ay += f0.y;
    }
    float ox = ax + __shfl(ax, lane + 32);
    float oy = ay + __shfl(ay, lane + 32);
    if (half == 0) {
        ox *= di; oy *= di;
        if (ADD_BIAS) {
            const float2 bv = ((const float2*)bias)[lc];
            ox += bv.x; oy += bv.y;
        }
        if (OUT_F16) ((unsigned*)outp)[(size_t)d * 32 + lc] = pk2(ox, oy);
        else         ((float2*)outp)[(size_t)d * 32 + lc] = make_float2(ox, oy);
    }
}

// r[row][c] = relu(sum_k agg_x[row][k] * W3[k][c] + b3[c]), r stored f16x2.
__global__ __launch_bounds__(256) void gemm1_kernel(
    const unsigned* __restrict__ xh, const float* __restrict__ W,
    const float* __restrict__ b, unsigned* __restrict__ rout, int n)
{
    __shared__ float Ws[IN_C * HID_C];   // 32 KB
    __shared__ float xs[64][IN_C + 1];   // 16.6 KB
    for (int i = threadIdx.x; i < IN_C * HID_C; i += 256) Ws[i] = W[i];
    const int r0 = blockIdx.x * 64;
    for (int i = threadIdx.x; i < 64 * 32; i += 256) {
        int row = i >> 5, c = i & 31;
        int r = r0 + row;
        float2 f = up2((r < n) ? xh[(size_t)r * 32 + c] : 0u);
        xs[row][c * 2]     = f.x;
        xs[row][c * 2 + 1] = f.y;
    }
    __syncthreads();
    const int ct = threadIdx.x & 15;   // 16 x 8 = 128 cols
    const int rt = threadIdx.x >> 4;   // 16 x 4 = 64 rows
    float acc[4][8] = {};
    const float4* Ws4 = (const float4*)Ws;
    for (int k = 0; k < IN_C; ++k) {
        float4 w0 = Ws4[k * 32 + ct * 2];
        float4 w1 = Ws4[k * 32 + ct * 2 + 1];
        #pragma unroll
        for (int ry = 0; ry < 4; ++ry) {
            float xv = xs[rt * 4 + ry][k];
            acc[ry][0] += xv * w0.x; acc[ry][1] += xv * w0.y;
            acc[ry][2] += xv * w0.z; acc[ry][3] += xv * w0.w;
            acc[ry][4] += xv * w1.x; acc[ry][5] += xv * w1.y;
            acc[ry][6] += xv * w1.z; acc[ry][7] += xv * w1.w;
        }
    }
    float4 b0 = ((const float4*)b)[ct * 2];
    float4 b1 = ((const float4*)b)[ct * 2 + 1];
    #pragma unroll
    for (int ry = 0; ry < 4; ++ry) {
        int r = r0 + rt * 4 + ry;
        if (r < n) {
            uint4 o;
            o.x = pk2(fmaxf(acc[ry][0] + b0.x, 0.0f), fmaxf(acc[ry][1] + b0.y, 0.0f));
            o.y = pk2(fmaxf(acc[ry][2] + b0.z, 0.0f), fmaxf(acc[ry][3] + b0.w, 0.0f));
            o.z = pk2(fmaxf(acc[ry][4] + b1.x, 0.0f), fmaxf(acc[ry][5] + b1.y, 0.0f));
            o.w = pk2(fmaxf(acc[ry][6] + b1.z, 0.0f), fmaxf(acc[ry][7] + b1.w, 0.0f));
            *(uint4*)&rout[(size_t)r * 64 + ct * 4] = o;
        }
    }
}

// t[row][c] = dinv[row] * sum_k r[row][k] * W4[k][c], stored f16x2.
__global__ __launch_bounds__(256) void gemm2_kernel(
    const unsigned* __restrict__ rin, const float* __restrict__ W,
    const float* __restrict__ dinv, unsigned* __restrict__ tout, int n)
{
    __shared__ unsigned Wh[HID_C * 32];  // 16 KB
    __shared__ float xs[64][HID_C + 1];  // 33 KB
    for (int i = threadIdx.x; i < HID_C * 32; i += 256) {
        int k = i >> 5, cp = i & 31;
        Wh[i] = pk2(W[k * OUT_C + cp * 2], W[k * OUT_C + cp * 2 + 1]);
    }
    const int r0 = blockIdx.x * 64;
    for (int i = threadIdx.x; i < 64 * 64; i += 256) {
        int row = i >> 6, c = i & 63;
        int r = r0 + row;
        float2 f = up2((r < n) ? rin[(size_t)r * 64 + c] : 0u);
        xs[row][c * 2]     = f.x;
        xs[row][c * 2 + 1] = f.y;
    }
    __syncthreads();
    const int ct = threadIdx.x & 7;    // 8 x 8 = 64 cols
    const int rt = threadIdx.x >> 3;   // 32 x 2 = 64 rows
    float acc[2][8] = {};
    for (int k = 0; k < HID_C; ++k) {
        uint4 wq = *(const uint4*)&Wh[k * 32 + ct * 4];
        float2 wa = up2(wq.x), wb = up2(wq.y), wc = up2(wq.z), wd = up2(wq.w);
        #pragma unroll
        for (int ry = 0; ry < 2; ++ry) {
            float xv = xs[rt * 2 + ry][k];
            acc[ry][0] += xv * wa.x; acc[ry][1] += xv * wa.y;
            acc[ry][2] += xv * wb.x; acc[ry][3] += xv * wb.y;
            acc[ry][4] += xv * wc.x; acc[ry][5] += xv * wc.y;
            acc[ry][6] += xv * wd.x; acc[ry][7] += xv * wd.y;
        }
    }
    #pragma unroll
    for (int ry = 0; ry < 2; ++ry) {
        int r = r0 + rt * 2 + ry;
        if (r < n) {
            float dv = dinv[r];
            uint4 o;
            o.x = pk2(acc[ry][0] * dv, acc[ry][1] * dv);
            o.y = pk2(acc[ry][2] * dv, acc[ry][3] * dv);
            o.z = pk2(acc[ry][4] * dv, acc[ry][5] * dv);
            o.w = pk2(acc[ry][6] * dv, acc[ry][7] * dv);
            *(uint4*)&tout[(size_t)r * 32 + ct * 4] = o;
        }
    }
}

extern "C" void kernel_launch(void* const* d_in, const int* in_sizes, int n_in,
                              void* d_out, int out_size, void* d_ws, size_t ws_size,
                              hipStream_t stream)
{
    const float* x  = (const float*)d_in[0];
    const int*   ei = (const int*)d_in[1];
    const float* W3 = (const float*)d_in[2];
    const float* b3 = (const float*)d_in[3];
    const float* W4 = (const float*)d_in[4];
    const float* b4 = (const float*)d_in[5];
    float* out = (float*)d_out;

    const int n = in_sizes[0] / IN_C;   // 100000
    const int E = in_sizes[1] / 2;      // 1600000
    const int* src = ei;
    const int* dst = ei + E;
    const int nbkt = (n + BW - 1) >> BSHIFT;   // 196

    const size_t n_pad = ((size_t)n + 256) & ~(size_t)255;  // room for row_start[n]

    // Workspace: bcnt(256) | bbase(512) | bcur(256) | row_start | dinv |
    //            ssrc | ebuf (E u32) | xh (n*32 u32, reused as t) |
    //            agg_x (n*32 u32) | r (n*64 u32)
    int*      bcnt      = (int*)d_ws;
    int*      bbase     = bcnt + 256;
    int*      bcur      = bbase + 512;
    int*      row_start = bcur + 256;
    float*    dinv      = (float*)(row_start + n_pad);
    int*      ssrc      = (int*)(dinv + n_pad);
    unsigned* ebuf      = (unsigned*)(ssrc + (((size_t)E + 255) & ~(size_t)255));
    unsigned* xh        = ebuf + (((size_t)E + 255) & ~(size_t)255);
    unsigned* agg_x     = xh + n_pad * 32;
    unsigned* r         = agg_x + n_pad * 32;
    unsigned* t         = xh;                      // xh dead after agg1

    zero_small_kernel<<<1, 256, 0, stream>>>(bcnt, 256);
    bhist_kernel<<<256, 256, 0, stream>>>(dst, bcnt, E, nbkt);
    bscan_kernel<<<1, 256, 0, stream>>>(bcnt, bbase, bcur, nbkt);

    bin_kernel<<<(E + TILE - 1) / TILE, 256, 0, stream>>>(src, dst, bcur, ebuf, E, nbkt);
    bucket_kernel<<<nbkt, 256, 0, stream>>>(ebuf, bbase, row_start, dinv, ssrc, n, E, nbkt);

    cvt_scaled_kernel<<<(n * 32 + 255) / 256, 256, 0, stream>>>(
        (const float2*)x, dinv, xh, n * 32);

    agg_f16_kernel<true, false><<<(n + 3) / 4, 256, 0, stream>>>(
        xh, row_start, ssrc, dinv, nullptr, agg_x, n);

    gemm1_kernel<<<(n + 63) / 64, 256, 0, stream>>>(agg_x, W3, b3, r, n);
    gemm2_kernel<<<(n + 63) / 64, 256, 0, stream>>>(r, W4, dinv, t, n);

    agg_f16_kernel<false, true><<<(n + 3) / 4, 256, 0, stream>>>(
        t, row_start, ssrc, dinv, b4, out, n);
}